// Round 8
// baseline (245.298 us; speedup 1.0000x reference)
//
#include <hip/hip_runtime.h>
#include <hip/hip_bf16.h>

typedef unsigned short u16;
typedef unsigned int u32;

#define B_ 4
#define N_ 4096
#define C_ 256
#define NH_ 8
#define HD_ 32
#define L_ 9
#define P_ 64
#define T_ 4096
#define NEG_ (-1e30f)

typedef __attribute__((ext_vector_type(8))) short bf16x8;
typedef __attribute__((ext_vector_type(4))) float f32x4;

__device__ __forceinline__ float b2f(u16 u) {
    union { u32 i; float f; } v; v.i = ((u32)u) << 16; return v.f;
}
__device__ __forceinline__ u16 f2b(float f) {
    u32 x = __float_as_uint(f);
    u32 r = (x + 0x7fffu + ((x >> 16) & 1u)) >> 16;
    return (u16)r;
}
__device__ __forceinline__ short f2bs(float f) { return (short)f2b(f); }
// HW packed f32->bf16 (lo = a, hi = b). Used ONLY in compensated hi/lo pairs,
// where hi rounding mode is irrelevant (lo carries the exact residual).
__device__ __forceinline__ u32 cvtpk(float a, float b) {
    u32 r; asm("v_cvt_pk_bf16_f32 %0, %1, %2" : "=v"(r) : "v"(a), "v"(b)); return r;
}
union U8 { u32 u[4]; bf16x8 v; };

// ---------------- prep: x->bf16, weights->bf16 (fused W), CPB MLP — one launch ----------------
// CPB output written TRANSPOSED: cpb[h][t] (h-major) -> each head's slice is a contiguous
// 16KB block, L2-resident for attn_k's value gathers.
__global__ __launch_bounds__(256) void prep_k(
    const float* __restrict__ x, const float* __restrict__ q_w, const float* __restrict__ kv_w,
    const float* __restrict__ sr_w, const float* __restrict__ proj_w,
    u16* __restrict__ xb, u16* __restrict__ wfused, u16* __restrict__ pwb,
    const float* __restrict__ table, const float* __restrict__ w1, const float* __restrict__ b1,
    const float* __restrict__ w2, const float* __restrict__ b2, float* __restrict__ cpb)
{
    __shared__ float w1s[512][2];
    __shared__ float b1s[512];
    __shared__ float w2s[8][512];
    int bid = blockIdx.x, tid = threadIdx.x;
    if (bid < 4096) {
        int i = bid * 256 + tid;
        float4 v = reinterpret_cast<const float4*>(x)[i];
        ushort4 o; o.x = f2b(v.x); o.y = f2b(v.y); o.z = f2b(v.z); o.w = f2b(v.w);
        reinterpret_cast<ushort4*>(xb)[i] = o;
    } else if (bid < 4416) {
        int i = (bid - 4096) * 256 + tid;
        const float* s; u16* d; int off;
        if (i < 16384)      { s = q_w;    d = wfused; off = i; }
        else if (i < 49152) { s = kv_w;   d = wfused; off = i; }
        else if (i < 65536) { s = sr_w;   d = wfused; off = i; }
        else                { s = proj_w; d = pwb;    off = i - 65536; }
        int soff = (i < 16384) ? i : (i < 49152) ? (i - 16384) : (i < 65536) ? (i - 49152) : (i - 65536);
        float4 v = reinterpret_cast<const float4*>(s)[soff];
        ushort4 o; o.x = f2b(v.x); o.y = f2b(v.y); o.z = f2b(v.z); o.w = f2b(v.w);
        reinterpret_cast<ushort4*>(d)[off] = o;
    } else {
        for (int i = tid; i < 512; i += 256) {
            w1s[i][0] = w1[i * 2]; w1s[i][1] = w1[i * 2 + 1]; b1s[i] = b1[i];
        }
        for (int i = tid; i < 4096; i += 256) w2s[i >> 9][i & 511] = w2[i];
        __syncthreads();
        int t = (bid - 4416) * 256 + tid;
        float t0 = table[t * 2], t1 = table[t * 2 + 1];
        float acc[8] = {};
        for (int j = 0; j < 512; ++j) {
            float h = fmaxf(t0 * w1s[j][0] + t1 * w1s[j][1] + b1s[j], 0.0f);
            #pragma unroll
            for (int hh = 0; hh < 8; ++hh) acc[hh] += h * w2s[hh][j];
        }
        #pragma unroll
        for (int hh = 0; hh < 8; ++hh) cpb[hh * 4096 + t] = acc[hh] + b2[hh];
    }
}

// ---------------- LDS-staged MFMA GEMM ----------------
// MODE 0: fused kv/sr. 1-D grid 768 = 8 xcd x 12 colblk x 8 ygrp, XCD-swizzled so all 12
//         column-blocks of one 256-row A-panel land on the SAME XCD.
// MODE 1: proj. 1-D grid 1024 = 8 xcd x 4 colblk x 32 ygrp, same scheme.
template<int MODE>
__global__ __launch_bounds__(256) void gemm_big_k(
    const u16* __restrict__ A, const u16* __restrict__ W,
    const float* __restrict__ b0, const float* __restrict__ b1, const float* __restrict__ b2,
    float* __restrict__ kvk, u16* __restrict__ kvv, u16* __restrict__ xgb, float* __restrict__ pout)
{
    constexpr int RI = (MODE == 0) ? 4 : 1;
    __shared__ u16 Bs[64 * 264];
    int tid = threadIdx.x, w = tid >> 6, lane = tid & 63;
    int quad = lane >> 4, l16 = lane & 15;
    int bx, by;
    {
        int i = blockIdx.x;
        if (MODE == 0) { bx = (i >> 3) % 12; by = (i & 7) + (i / 96) * 8; }
        else           { bx = (i >> 3) & 3;  by = (i & 7) + (i / 32) * 8; }
    }
    int colBase = (MODE == 0 ? 256 : 0) + bx * 64;
    #pragma unroll
    for (int c = 0; c < 8; ++c) {
        int linear = c * 256 + tid;
        int col = linear >> 5, kc = linear & 31;
        uint4 v = *reinterpret_cast<const uint4*>(W + (size_t)(colBase + col) * 256 + kc * 8);
        *reinterpret_cast<uint4*>(&Bs[col * 264 + kc * 8]) = v;
    }
    __syncthreads();
    int rowBase = by * (RI * 64) + w * (RI * 16);
    f32x4 acc[RI][4] = {};
    const u16* aptr = A + (size_t)(rowBase + l16) * 256 + quad * 8;
    bf16x8 afc[RI];
    #pragma unroll
    for (int i = 0; i < RI; ++i) afc[i] = *reinterpret_cast<const bf16x8*>(aptr + (size_t)i * 16 * 256);
    #pragma unroll
    for (int k0 = 0; k0 < 256; k0 += 32) {
        bf16x8 afn[RI];
        if (k0 < 224) {
            #pragma unroll
            for (int i = 0; i < RI; ++i)
                afn[i] = *reinterpret_cast<const bf16x8*>(aptr + (size_t)i * 16 * 256 + k0 + 32);
        }
        #pragma unroll
        for (int j = 0; j < 4; ++j) {
            bf16x8 bfr = *reinterpret_cast<const bf16x8*>(&Bs[(j * 16 + l16) * 264 + k0 + quad * 8]);
            #pragma unroll
            for (int i = 0; i < RI; ++i)
                acc[i][j] = __builtin_amdgcn_mfma_f32_16x16x32_bf16(afc[i], bfr, acc[i][j], 0, 0, 0);
        }
        if (k0 < 224) {
            #pragma unroll
            for (int i = 0; i < RI; ++i) afc[i] = afn[i];
        }
    }
    int rng = (MODE == 0) ? (colBase >> 8) : 99;   // 1:kv-k 2:kv-v 3:sr
    float bj[4];
    #pragma unroll
    for (int j = 0; j < 4; ++j) {
        int gc = colBase + j * 16 + l16;
        if (MODE == 1)      bj[j] = b0[gc];
        else if (rng <= 2)  bj[j] = b1[gc - 256];
        else                bj[j] = b2[gc - 768];
    }
    #pragma unroll
    for (int i = 0; i < RI; ++i) {
        float vals[4][4];
        #pragma unroll
        for (int j = 0; j < 4; ++j)
            #pragma unroll
            for (int r = 0; r < 4; ++r) {
                float t = acc[i][j][r] + bj[j];
                if (MODE == 0 && rng == 3) t = 0.5f * t * (1.0f + erff(t * 0.70710678118654752f));
                vals[j][r] = t;
            }
        if (MODE == 0 && rng == 1) {
            #pragma unroll
            for (int hp = 0; hp < 2; ++hp)
                #pragma unroll
                for (int r = 0; r < 4; ++r) {
                    float s = vals[2*hp][r] * vals[2*hp][r] + vals[2*hp+1][r] * vals[2*hp+1][r];
                    s += __shfl_xor(s, 1); s += __shfl_xor(s, 2);
                    s += __shfl_xor(s, 4); s += __shfl_xor(s, 8);
                    float inv = 1.0f / fmaxf(sqrtf(s), 1e-12f);
                    vals[2*hp][r] *= inv; vals[2*hp+1][r] *= inv;
                }
        }
        #pragma unroll
        for (int j = 0; j < 4; ++j) {
            int gc = colBase + j * 16 + l16;
            #pragma unroll
            for (int r = 0; r < 4; ++r) {
                int row = rowBase + i * 16 + quad * 4 + r;
                if (MODE == 1)      pout[(size_t)row * 256 + gc] = vals[j][r];
                else if (rng == 1)  kvk[(size_t)row * 256 + gc - 256] = vals[j][r];
                else if (rng == 2)  kvv[(size_t)row * 256 + gc - 512] = f2b(vals[j][r]);
                else                xgb[(size_t)row * 256 + gc - 768] = f2b(vals[j][r]);
            }
        }
    }
}

// ---------------- fused avgpool+LN+kv_pool+k-norm: ONE block per (b,p), 256 blocks ----------------
__global__ __launch_bounds__(256) void poolkv_k(
    const u16* __restrict__ xgb, const float* __restrict__ g, const float* __restrict__ bta,
    const float* __restrict__ kv_w, const float* __restrict__ kv_b, float* __restrict__ kvp)
{
    int bp = blockIdx.x;
    int tid = threadIdx.x;
    __shared__ __align__(16) float xps[256];
    __shared__ float r1[4], r2[4];
    int b = bp >> 6, p = bp & 63;
    int py = p >> 3, px = p & 7;
    int o = tid;
    float s = 0.0f;
    for (int sy = 0; sy < 8; ++sy)
        #pragma unroll
        for (int sx = 0; sx < 8; ++sx) {
            int pix = (py * 8 + sy) * 64 + px * 8 + sx;
            s += b2f(xgb[((size_t)(b * N_ + pix)) * C_ + o]);
        }
    float v = s * (1.0f / 64.0f);
    float s1 = v, s2 = v * v;
    #pragma unroll
    for (int off = 32; off >= 1; off >>= 1) { s1 += __shfl_xor(s1, off); s2 += __shfl_xor(s2, off); }
    int wv = o >> 6, ln = o & 63;
    if (ln == 0) { r1[wv] = s1; r2[wv] = s2; }
    __syncthreads();
    float S1 = r1[0] + r1[1] + r1[2] + r1[3];
    float S2 = r2[0] + r2[1] + r2[2] + r2[3];
    float mu = S1 * (1.0f / 256.0f);
    float var = S2 * (1.0f / 256.0f) - mu * mu;
    xps[o] = (v - mu) * rsqrtf(var + 1e-5f) * g[o] + bta[o];
    __syncthreads();
    float a0 = kv_b[o];          // k column
    float a1 = kv_b[256 + o];    // v column
    const float4* xp4 = (const float4*)xps;
    const float4* wrow0 = (const float4*)(kv_w + (size_t)o * 256);
    const float4* wrow1 = (const float4*)(kv_w + (size_t)(256 + o) * 256);
    #pragma unroll 8
    for (int k4 = 0; k4 < 64; ++k4) {
        float4 xv = xp4[k4];
        float4 wa = wrow0[k4];
        float4 wb = wrow1[k4];
        a0 += xv.x * wa.x + xv.y * wa.y + xv.z * wa.z + xv.w * wa.w;
        a1 += xv.x * wb.x + xv.y * wb.y + xv.z * wb.z + xv.w * wb.w;
    }
    {
        float ss = a0 * a0;
        ss += __shfl_xor(ss, 1); ss += __shfl_xor(ss, 2); ss += __shfl_xor(ss, 4);
        ss += __shfl_xor(ss, 8); ss += __shfl_xor(ss, 16);
        a0 *= 1.0f / fmaxf(sqrtf(ss), 1e-12f);
    }
    kvp[(size_t)bp * 512 + o]       = a0;
    kvp[(size_t)bp * 512 + 256 + o] = a1;
}

// ---------------- MFMA fused attention: 2-tile loop; cpb VALUE gather (no LDS stage) ----------------
// LDS back to 35400 B (round-7's cpb_s 16KB stage removed) -> 4 blocks/CU by LDS, and
// 1024 blocks = 4 x 256 CU runs in ONE round (no ragged tail). cpb is 128KB total / 16KB
// per head, read 32x per (b,h) -> L2-resident; the 16 value gathers (rpi -> cpbt, 2-deep
// dependent chain ~400cy) are hoisted to tile start and hide under the 16-MFMA q-GEMM.
__global__ __launch_bounds__(256) void attn_k(
    const u16* __restrict__ xb, const u16* __restrict__ qwb, const float* __restrict__ q_b,
    const float* __restrict__ kvk, const u16* __restrict__ kvv,
    const float* __restrict__ kvp, const int* __restrict__ rpi, const float* __restrict__ cpbt,
    const float* __restrict__ temp, const float* __restrict__ qe, const float* __restrict__ lt,
    const float* __restrict__ rpb, const float* __restrict__ lb,
    const float* __restrict__ slsin, u16* __restrict__ aob)
{
    __shared__ u16 kp_hi[64 * 40], kp_lo[64 * 40];
    __shared__ u16 vp_hi[32 * 72];
    __shared__ u16 ltb[16 * 32];
    __shared__ float S_w[4][16][76];
    __shared__ float rpb_s[9], lb_s[9];

    int bid = blockIdx.x;
    int tq = bid & 31, h = (bid >> 5) & 7, b = bid >> 8;
    int tid = threadIdx.x, wave = tid >> 6, lane = tid & 63;
    int quad = lane >> 4, l16 = lane & 15;

    {
        int p = tid >> 2, dc = (tid & 3) * 8;
        const float* src = kvp + ((size_t)(b * P_ + p)) * 512 + h * 32 + dc;
        float4 k0 = *(const float4*)(src), k1 = *(const float4*)(src + 4);
        float4 v0 = *(const float4*)(src + 256), v1 = *(const float4*)(src + 260);
        float kf[8] = {k0.x,k0.y,k0.z,k0.w,k1.x,k1.y,k1.z,k1.w};
        float vf[8] = {v0.x,v0.y,v0.z,v0.w,v1.x,v1.y,v1.z,v1.w};
        #pragma unroll
        for (int j2 = 0; j2 < 4; ++j2) {
            float a = kf[2*j2], c = kf[2*j2+1];
            u32 pk = cvtpk(a, c);
            *(u32*)&kp_hi[p * 40 + dc + 2*j2] = pk;
            float ra = __uint_as_float(pk << 16);
            float rb = __uint_as_float(pk & 0xffff0000u);
            *(u32*)&kp_lo[p * 40 + dc + 2*j2] = cvtpk(a - ra, c - rb);
            // vp_hi uncompensated -> keep bit-exact RNE f2b
            vp_hi[(dc + 2*j2) * 72 + p]     = f2b(vf[2*j2]);
            vp_hi[(dc + 2*j2 + 1) * 72 + p] = f2b(vf[2*j2+1]);
        }
    }
    for (int t = tid; t < 512; t += 256) {
        int l = t & 15, d = t >> 4;
        ltb[l * 32 + d] = (l < 9) ? f2b(lt[h * 288 + d * 9 + l]) : (u16)0;
    }
    if (tid < 9) { rpb_s[tid] = rpb[h * 9 + tid]; lb_s[tid] = lb[h * 9 + tid]; }
    float tsc = log1pf(expf(temp[h]));
    __syncthreads();

    const float* cpb_h = cpbt + (size_t)h * 4096;

    #pragma unroll 1
    for (int it = 0; it < 2; ++it) {
        int tile = tq * 2 + it;
        int n0w = tile * 64 + wave * 16;
        int y = tile;

        // ---- hoisted pool-bias VALUE gather: rpi -> cpbt (both L2-resident), issued before
        //      the q-GEMM so the ~400cy dependent chain hides under the 16-MFMA cluster ----
        float bv[16];
        #pragma unroll
        for (int jt = 0; jt < 4; ++jt)
            #pragma unroll
            for (int r = 0; r < 4; ++r)
                bv[jt * 4 + r] = cpb_h[rpi[(size_t)(n0w + quad * 4 + r) * 64 + jt * 16 + l16]];

        // ---- fused q-GEMM: 64x32 slice via 16 MFMA ----
        f32x4 qacc[2] = {};
        {
            const u16* xrow = xb + ((size_t)(b * N_ + n0w + l16)) * 256 + quad * 8;
            const u16* qwr  = qwb + ((size_t)(h * 32 + l16)) * 256 + quad * 8;
            #pragma unroll
            for (int k0 = 0; k0 < 256; k0 += 32) {
                bf16x8 ax = *(const bf16x8*)(xrow + k0);
                bf16x8 bw0 = *(const bf16x8*)(qwr + k0);
                bf16x8 bw1 = *(const bf16x8*)(qwr + 16 * 256 + k0);
                qacc[0] = __builtin_amdgcn_mfma_f32_16x16x32_bf16(ax, bw0, qacc[0], 0, 0, 0);
                qacc[1] = __builtin_amdgcn_mfma_f32_16x16x32_bf16(ax, bw1, qacc[1], 0, 0, 0);
            }
        }
        {
            float qb0 = q_b[h * 32 + l16], qb1 = q_b[h * 32 + 16 + l16];
            float qe0 = qe[h * 32 + l16],  qe1 = qe[h * 32 + 16 + l16];
            #pragma unroll
            for (int r = 0; r < 4; ++r) {
                int p = quad * 4 + r;
                float v0 = qacc[0][r] + qb0, v1 = qacc[1][r] + qb1;
                float s = v0 * v0 + v1 * v1;
                s += __shfl_xor(s, 1); s += __shfl_xor(s, 2);
                s += __shfl_xor(s, 4); s += __shfl_xor(s, 8);
                float inv = 1.0f / fmaxf(sqrtf(s), 1e-12f);
                v0 *= inv; v1 *= inv;
                float sc = tsc * slsin[n0w + p];
                S_w[wave][p][40 + l16]      = (v0 + qe0) * sc;
                S_w[wave][p][40 + 16 + l16] = (v1 + qe1) * sc;
            }
        }
        // ---- rebuild per-lane fragments (A-layout) from qs scratch in S_w cols 40..71 ----
        bf16x8 qs_hi, qs_lo, qn_b;
        float qsr[8];
        {
            *(float4*)&qsr[0] = *(const float4*)&S_w[wave][l16][40 + quad * 8];
            *(float4*)&qsr[4] = *(const float4*)&S_w[wave][l16][40 + quad * 8 + 4];
            float invs = 1.0f / (tsc * slsin[n0w + l16]);
            const float* qep = qe + h * 32 + quad * 8;
            float4 e0 = *(const float4*)qep, e1 = *(const float4*)(qep + 4);
            float ef[8] = {e0.x,e0.y,e0.z,e0.w,e1.x,e1.y,e1.z,e1.w};
            U8 hiu, lou;
            #pragma unroll
            for (int j2 = 0; j2 < 4; ++j2) {
                float a = qsr[2*j2], c = qsr[2*j2+1];
                u32 pk = cvtpk(a, c);
                hiu.u[j2] = pk;
                float ra = __uint_as_float(pk << 16);
                float rb = __uint_as_float(pk & 0xffff0000u);
                lou.u[j2] = cvtpk(a - ra, c - rb);
            }
            qs_hi = hiu.v; qs_lo = lou.v;
            #pragma unroll
            for (int j = 0; j < 8; ++j)
                qn_b[j] = f2bs(qsr[j] * invs - ef[j]);   // uncompensated -> exact RNE
        }
        // ---- pool logits (12 MFMA, compensated) + gathered bias ----
        __builtin_amdgcn_s_setprio(1);
        #pragma unroll
        for (int jt = 0; jt < 4; ++jt) {
            bf16x8 bh = *(const bf16x8*)&kp_hi[(jt * 16 + l16) * 40 + quad * 8];
            bf16x8 bl = *(const bf16x8*)&kp_lo[(jt * 16 + l16) * 40 + quad * 8];
            f32x4 a = {};
            a = __builtin_amdgcn_mfma_f32_16x16x32_bf16(qs_lo, bh, a, 0, 0, 0);
            a = __builtin_amdgcn_mfma_f32_16x16x32_bf16(qs_hi, bl, a, 0, 0, 0);
            a = __builtin_amdgcn_mfma_f32_16x16x32_bf16(qs_hi, bh, a, 0, 0, 0);
            #pragma unroll
            for (int r = 0; r < 4; ++r) {
                int pix = quad * 4 + r;
                S_w[wave][pix][jt * 16 + l16] = a[r] + bv[jt * 4 + r];
            }
        }
        __builtin_amdgcn_s_setprio(0);
        // ---- learnable-token logits (1 MFMA) ----
        f32x4 accL;
        {
            bf16x8 ltf = *(const bf16x8*)&ltb[l16 * 32 + quad * 8];
            f32x4 z = {};
            accL = __builtin_amdgcn_mfma_f32_16x16x32_bf16(qn_b, ltf, z, 0, 0, 0);
        }
        // ---- local 3x3 logits: register qs + cross-quad shuffle reduce ----
        #pragma unroll
        for (int l = 0; l < 9; ++l) {
            int n = n0w + l16, x = n & 63;
            int ny = y + l / 3 - 1, nx = x + (l % 3) - 1;
            bool ok = ((unsigned)ny < 64u) && ((unsigned)nx < 64u);
            int nn = ok ? ny * 64 + nx : n;
            const float4* kb = (const float4*)(kvk + ((size_t)(b * N_ + nn)) * 256 + h * 32 + quad * 8);
            float4 k0v = kb[0], k1v = kb[1];
            float part = qsr[0]*k0v.x + qsr[1]*k0v.y + qsr[2]*k0v.z + qsr[3]*k0v.w
                       + qsr[4]*k1v.x + qsr[5]*k1v.y + qsr[6]*k1v.z + qsr[7]*k1v.w;
            part += __shfl_xor(part, 16);
            part += __shfl_xor(part, 32);
            if (quad == 0) S_w[wave][l16][64 + l] = ok ? (part + rpb_s[l]) : NEG_;
        }
        // ---- re-init NEG pad (softmax of previous tile / qs scratch overwrote it) ----
        if (quad == 0) { S_w[wave][l16][73] = NEG_; S_w[wave][l16][74] = NEG_; S_w[wave][l16][75] = NEG_; }
        // ---- softmax over 73 (4 lanes per pixel, 19 cols each) ----
        {
            int pix = lane >> 2, c0 = (lane & 3) * 19;
            float vals[19]; float mx = NEG_;
            #pragma unroll
            for (int i = 0; i < 19; ++i) { vals[i] = S_w[wave][pix][c0 + i]; mx = fmaxf(mx, vals[i]); }
            mx = fmaxf(mx, __shfl_xor(mx, 1));
            mx = fmaxf(mx, __shfl_xor(mx, 2));
            float sm = 0.0f;
            #pragma unroll
            for (int i = 0; i < 19; ++i) { vals[i] = __expf(vals[i] - mx); sm += vals[i]; }
            sm += __shfl_xor(sm, 1); sm += __shfl_xor(sm, 2);
            float inv = 1.0f / sm;
            #pragma unroll
            for (int i = 0; i < 19; ++i) S_w[wave][pix][c0 + i] = vals[i] * inv;
        }
        // ---- combined local weights overwrite S_w cols 64..72 ----
        if (l16 < 9) {
            #pragma unroll
            for (int r = 0; r < 4; ++r) {
                int pix = quad * 4 + r;
                int n = n0w + pix, x = n & 63;
                int ny = y + l16 / 3 - 1, nx = x + (l16 % 3) - 1;
                bool ok = ((unsigned)ny < 64u) && ((unsigned)nx < 64u);
                float prev = S_w[wave][pix][64 + l16];
                S_w[wave][pix][64 + l16] = ok ? (accL[r] + lb_s[l16] + prev) : 0.0f;
            }
        }
        // ---- PV (8 MFMA: (w_hi + w_lo) x v_hi) ----
        f32x4 accO[2] = {};
        __builtin_amdgcn_s_setprio(1);
        #pragma unroll
        for (int kc = 0; kc < 2; ++kc) {
            float wf[8];
            *(float4*)&wf[0] = *(const float4*)&S_w[wave][l16][kc * 32 + quad * 8];
            *(float4*)&wf[4] = *(const float4*)&S_w[wave][l16][kc * 32 + quad * 8 + 4];
            U8 hiu, lou;
            #pragma unroll
            for (int j2 = 0; j2 < 4; ++j2) {
                float a = wf[2*j2], c = wf[2*j2+1];
                u32 pk = cvtpk(a, c);
                hiu.u[j2] = pk;
                float ra = __uint_as_float(pk << 16);
                float rb = __uint_as_float(pk & 0xffff0000u);
                lou.u[j2] = cvtpk(a - ra, c - rb);
            }
            bf16x8 w_hi = hiu.v, w_lo = lou.v;
            #pragma unroll
            for (int nt = 0; nt < 2; ++nt) {
                bf16x8 vh = *(const bf16x8*)&vp_hi[(nt * 16 + l16) * 72 + kc * 32 + quad * 8];
                accO[nt] = __builtin_amdgcn_mfma_f32_16x16x32_bf16(w_lo, vh, accO[nt], 0, 0, 0);
                accO[nt] = __builtin_amdgcn_mfma_f32_16x16x32_bf16(w_hi, vh, accO[nt], 0, 0, 0);
            }
        }
        __builtin_amdgcn_s_setprio(0);
        // ---- local-V: shared neighbor columns per quad (18 cols x 2 dims) ----
        {
            int xq0 = wave * 16 + quad * 4;     // x of pixel r=0
            #pragma unroll
            for (int dy = -1; dy <= 1; ++dy) {
                int ny = y + dy;
                bool rowOK = ((unsigned)ny < 64u);
                #pragma unroll
                for (int c = 0; c < 6; ++c) {
                    int xc = xq0 - 1 + c;
                    bool ok = rowOK && ((unsigned)xc < 64u);
                    int nn = ok ? ny * 64 + xc : 0;
                    const u16* vb = kvv + ((size_t)(b * N_ + nn)) * 256 + h * 32;
                    float v0 = b2f(vb[l16]);
                    float v1 = b2f(vb[16 + l16]);
                    #pragma unroll
                    for (int r = 0; r < 4; ++r) {
                        int dxr = c - 1 - r;
                        if (dxr >= -1 && dxr <= 1) {
                            int l = (dy + 1) * 3 + dxr + 1;
                            float aw = S_w[wave][quad * 4 + r][64 + l];
                            accO[0][r] += aw * v0;
                            accO[1][r] += aw * v1;
                        }
                    }
                }
            }
        }
        #pragma unroll
        for (int nt = 0; nt < 2; ++nt)
            #pragma unroll
            for (int r = 0; r < 4; ++r) {
                int n = n0w + quad * 4 + r;
                aob[((size_t)(b * N_ + n)) * C_ + h * 32 + nt * 16 + l16] = f2b(accO[nt][r]);
            }
    }
}

extern "C" void kernel_launch(void* const* d_in, const int* in_sizes, int n_in,
                              void* d_out, int out_size, void* d_ws, size_t ws_size,
                              hipStream_t stream) {
    const float* x      = (const float*)d_in[0];
    const int*   rpi    = (const int*)d_in[1];
    const float* table  = (const float*)d_in[2];
    const float* q_w    = (const float*)d_in[3];
    const float* q_b    = (const float*)d_in[4];
    const float* kv_w   = (const float*)d_in[5];
    const float* kv_b   = (const float*)d_in[6];
    const float* temp   = (const float*)d_in[7];
    const float* qe     = (const float*)d_in[8];
    const float* proj_w = (const float*)d_in[9];
    const float* proj_b = (const float*)d_in[10];
    const float* sr_w   = (const float*)d_in[11];
    const float* sr_b   = (const float*)d_in[12];
    const float* norm_g = (const float*)d_in[13];
    const float* norm_b = (const float*)d_in[14];
    const float* cpb1_w = (const float*)d_in[15];
    const float* cpb1_b = (const float*)d_in[16];
    const float* cpb2_w = (const float*)d_in[17];
    const float* cpb2_b = (const float*)d_in[18];
    const float* rpb    = (const float*)d_in[19];
    const float* lt     = (const float*)d_in[20];
    const float* lb     = (const float*)d_in[21];
    const float* sls    = (const float*)d_in[22];

    float* ws   = (float*)d_ws;
    float* kvk  = ws;                                   // B*N*C fp32 (k, l2normed)
    float* kvp  = kvk + (size_t)B_ * N_ * C_;           // B*P*2C fp32
    float* cpb  = kvp + (size_t)B_ * P_ * 2 * C_;       // NH*T fp32 (transposed: [h][t])
    u16*   xb   = (u16*)(cpb + (size_t)T_ * NH_);       // B*N*C bf16
    u16*   wfb  = xb  + (size_t)B_ * N_ * C_;           // 1024*256 bf16 (q;kv;sr)
    u16*   pwb  = wfb + (size_t)1024 * C_;              // C*C bf16
    u16*   kvv  = pwb + (size_t)C_ * C_;                // B*N*C bf16 (v)
    u16*   xgb  = kvv + (size_t)B_ * N_ * C_;           // B*N*C bf16 (gelu out; reused as attn out)
    u16*   aob  = xgb;

    dim3 blk(256);

    prep_k<<<dim3(4432), blk, 0, stream>>>(x, q_w, kv_w, sr_w, proj_w, xb, wfb, pwb,
                                           table, cpb1_w, cpb1_b, cpb2_w, cpb2_b, cpb);
    gemm_big_k<0><<<dim3(768), blk, 0, stream>>>(xb, wfb, nullptr, kv_b, sr_b, kvk, kvv, xgb, nullptr);
    poolkv_k<<<dim3(256), blk, 0, stream>>>(xgb, norm_g, norm_b, kv_w, kv_b, kvp);
    attn_k<<<dim3(B_ * NH_ * 32), blk, 0, stream>>>(xb, wfb, q_b, kvk, kvv, kvp, rpi, cpb,
                                                    temp, qe, lt, rpb, lb, sls, aob);
    gemm_big_k<1><<<dim3(1024), blk, 0, stream>>>(aob, pwb, proj_b, nullptr, nullptr,
                                                  nullptr, nullptr, nullptr, (float*)d_out);
}

// Round 9
// 242.562 us; speedup vs baseline: 1.0113x; 1.0113x over previous
//
#include <hip/hip_runtime.h>
#include <hip/hip_bf16.h>

typedef unsigned short u16;
typedef unsigned int u32;

#define B_ 4
#define N_ 4096
#define C_ 256
#define NH_ 8
#define HD_ 32
#define L_ 9
#define P_ 64
#define T_ 4096
#define NEG_ (-1e30f)

typedef __attribute__((ext_vector_type(8))) short bf16x8;
typedef __attribute__((ext_vector_type(4))) float f32x4;

__device__ __forceinline__ float b2f(u16 u) {
    union { u32 i; float f; } v; v.i = ((u32)u) << 16; return v.f;
}
__device__ __forceinline__ u16 f2b(float f) {
    u32 x = __float_as_uint(f);
    u32 r = (x + 0x7fffu + ((x >> 16) & 1u)) >> 16;
    return (u16)r;
}
__device__ __forceinline__ short f2bs(float f) { return (short)f2b(f); }
// HW packed f32->bf16 (lo = a, hi = b). Used ONLY in compensated hi/lo pairs,
// where hi rounding mode is irrelevant (lo carries the exact residual).
__device__ __forceinline__ u32 cvtpk(float a, float b) {
    u32 r; asm("v_cvt_pk_bf16_f32 %0, %1, %2" : "=v"(r) : "v"(a), "v"(b)); return r;
}
union U8 { u32 u[4]; bf16x8 v; };

// ---------------- prep: x->bf16, weights->bf16 (fused W), CPB MLP — one launch ----------------
// CPB output is written TRANSPOSED: cpb[h][t] (h-major) so attn_k can stage one head's
// 16KB slice into LDS with coalesced float4 loads.
__global__ __launch_bounds__(256) void prep_k(
    const float* __restrict__ x, const float* __restrict__ q_w, const float* __restrict__ kv_w,
    const float* __restrict__ sr_w, const float* __restrict__ proj_w,
    u16* __restrict__ xb, u16* __restrict__ wfused, u16* __restrict__ pwb,
    const float* __restrict__ table, const float* __restrict__ w1, const float* __restrict__ b1,
    const float* __restrict__ w2, const float* __restrict__ b2, float* __restrict__ cpb)
{
    __shared__ float w1s[512][2];
    __shared__ float b1s[512];
    __shared__ float w2s[8][512];
    int bid = blockIdx.x, tid = threadIdx.x;
    if (bid < 4096) {
        int i = bid * 256 + tid;
        float4 v = reinterpret_cast<const float4*>(x)[i];
        ushort4 o; o.x = f2b(v.x); o.y = f2b(v.y); o.z = f2b(v.z); o.w = f2b(v.w);
        reinterpret_cast<ushort4*>(xb)[i] = o;
    } else if (bid < 4416) {
        int i = (bid - 4096) * 256 + tid;
        const float* s; u16* d; int off;
        if (i < 16384)      { s = q_w;    d = wfused; off = i; }
        else if (i < 49152) { s = kv_w;   d = wfused; off = i; }
        else if (i < 65536) { s = sr_w;   d = wfused; off = i; }
        else                { s = proj_w; d = pwb;    off = i - 65536; }
        int soff = (i < 16384) ? i : (i < 49152) ? (i - 16384) : (i < 65536) ? (i - 49152) : (i - 65536);
        float4 v = reinterpret_cast<const float4*>(s)[soff];
        ushort4 o; o.x = f2b(v.x); o.y = f2b(v.y); o.z = f2b(v.z); o.w = f2b(v.w);
        reinterpret_cast<ushort4*>(d)[off] = o;
    } else {
        for (int i = tid; i < 512; i += 256) {
            w1s[i][0] = w1[i * 2]; w1s[i][1] = w1[i * 2 + 1]; b1s[i] = b1[i];
        }
        for (int i = tid; i < 4096; i += 256) w2s[i >> 9][i & 511] = w2[i];
        __syncthreads();
        int t = (bid - 4416) * 256 + tid;
        float t0 = table[t * 2], t1 = table[t * 2 + 1];
        float acc[8] = {};
        for (int j = 0; j < 512; ++j) {
            float h = fmaxf(t0 * w1s[j][0] + t1 * w1s[j][1] + b1s[j], 0.0f);
            #pragma unroll
            for (int hh = 0; hh < 8; ++hh) acc[hh] += h * w2s[hh][j];
        }
        #pragma unroll
        for (int hh = 0; hh < 8; ++hh) cpb[hh * 4096 + t] = acc[hh] + b2[hh];
    }
}

// ---------------- LDS-staged MFMA GEMM ----------------
// MODE 0: fused kv/sr. 1-D grid 768 = 8 xcd x 12 colblk x 8 ygrp, XCD-swizzled so all 12
//         column-blocks of one 256-row A-panel land on the SAME XCD.
// MODE 1: proj. 1-D grid 1024 = 8 xcd x 4 colblk x 32 ygrp, same scheme.
template<int MODE>
__global__ __launch_bounds__(256) void gemm_big_k(
    const u16* __restrict__ A, const u16* __restrict__ W,
    const float* __restrict__ b0, const float* __restrict__ b1, const float* __restrict__ b2,
    float* __restrict__ kvk, u16* __restrict__ kvv, u16* __restrict__ xgb, float* __restrict__ pout)
{
    constexpr int RI = (MODE == 0) ? 4 : 1;
    __shared__ u16 Bs[64 * 264];
    int tid = threadIdx.x, w = tid >> 6, lane = tid & 63;
    int quad = lane >> 4, l16 = lane & 15;
    int bx, by;
    {
        int i = blockIdx.x;
        if (MODE == 0) { bx = (i >> 3) % 12; by = (i & 7) + (i / 96) * 8; }
        else           { bx = (i >> 3) & 3;  by = (i & 7) + (i / 32) * 8; }
    }
    int colBase = (MODE == 0 ? 256 : 0) + bx * 64;
    #pragma unroll
    for (int c = 0; c < 8; ++c) {
        int linear = c * 256 + tid;
        int col = linear >> 5, kc = linear & 31;
        uint4 v = *reinterpret_cast<const uint4*>(W + (size_t)(colBase + col) * 256 + kc * 8);
        *reinterpret_cast<uint4*>(&Bs[col * 264 + kc * 8]) = v;
    }
    __syncthreads();
    int rowBase = by * (RI * 64) + w * (RI * 16);
    f32x4 acc[RI][4] = {};
    const u16* aptr = A + (size_t)(rowBase + l16) * 256 + quad * 8;
    bf16x8 afc[RI];
    #pragma unroll
    for (int i = 0; i < RI; ++i) afc[i] = *reinterpret_cast<const bf16x8*>(aptr + (size_t)i * 16 * 256);
    #pragma unroll
    for (int k0 = 0; k0 < 256; k0 += 32) {
        bf16x8 afn[RI];
        if (k0 < 224) {
            #pragma unroll
            for (int i = 0; i < RI; ++i)
                afn[i] = *reinterpret_cast<const bf16x8*>(aptr + (size_t)i * 16 * 256 + k0 + 32);
        }
        #pragma unroll
        for (int j = 0; j < 4; ++j) {
            bf16x8 bfr = *reinterpret_cast<const bf16x8*>(&Bs[(j * 16 + l16) * 264 + k0 + quad * 8]);
            #pragma unroll
            for (int i = 0; i < RI; ++i)
                acc[i][j] = __builtin_amdgcn_mfma_f32_16x16x32_bf16(afc[i], bfr, acc[i][j], 0, 0, 0);
        }
        if (k0 < 224) {
            #pragma unroll
            for (int i = 0; i < RI; ++i) afc[i] = afn[i];
        }
    }
    int rng = (MODE == 0) ? (colBase >> 8) : 99;   // 1:kv-k 2:kv-v 3:sr
    float bj[4];
    #pragma unroll
    for (int j = 0; j < 4; ++j) {
        int gc = colBase + j * 16 + l16;
        if (MODE == 1)      bj[j] = b0[gc];
        else if (rng <= 2)  bj[j] = b1[gc - 256];
        else                bj[j] = b2[gc - 768];
    }
    #pragma unroll
    for (int i = 0; i < RI; ++i) {
        float vals[4][4];
        #pragma unroll
        for (int j = 0; j < 4; ++j)
            #pragma unroll
            for (int r = 0; r < 4; ++r) {
                float t = acc[i][j][r] + bj[j];
                if (MODE == 0 && rng == 3) t = 0.5f * t * (1.0f + erff(t * 0.70710678118654752f));
                vals[j][r] = t;
            }
        if (MODE == 0 && rng == 1) {
            #pragma unroll
            for (int hp = 0; hp < 2; ++hp)
                #pragma unroll
                for (int r = 0; r < 4; ++r) {
                    float s = vals[2*hp][r] * vals[2*hp][r] + vals[2*hp+1][r] * vals[2*hp+1][r];
                    s += __shfl_xor(s, 1); s += __shfl_xor(s, 2);
                    s += __shfl_xor(s, 4); s += __shfl_xor(s, 8);
                    float inv = 1.0f / fmaxf(sqrtf(s), 1e-12f);
                    vals[2*hp][r] *= inv; vals[2*hp+1][r] *= inv;
                }
        }
        #pragma unroll
        for (int j = 0; j < 4; ++j) {
            int gc = colBase + j * 16 + l16;
            #pragma unroll
            for (int r = 0; r < 4; ++r) {
                int row = rowBase + i * 16 + quad * 4 + r;
                if (MODE == 1)      pout[(size_t)row * 256 + gc] = vals[j][r];
                else if (rng == 1)  kvk[(size_t)row * 256 + gc - 256] = vals[j][r];
                else if (rng == 2)  kvv[(size_t)row * 256 + gc - 512] = f2b(vals[j][r]);
                else                xgb[(size_t)row * 256 + gc - 768] = f2b(vals[j][r]);
            }
        }
    }
}

// ---------------- fused avgpool+LN+kv_pool+k-norm: ONE block per (b,p), 256 blocks ----------------
// Each thread computes BOTH its k-col (tid) and v-col (256+tid) dot products from the shared
// xps -> xgb read once, pool/LN computed once.
__global__ __launch_bounds__(256) void poolkv_k(
    const u16* __restrict__ xgb, const float* __restrict__ g, const float* __restrict__ bta,
    const float* __restrict__ kv_w, const float* __restrict__ kv_b, float* __restrict__ kvp)
{
    int bp = blockIdx.x;
    int tid = threadIdx.x;
    __shared__ __align__(16) float xps[256];
    __shared__ float r1[4], r2[4];
    int b = bp >> 6, p = bp & 63;
    int py = p >> 3, px = p & 7;
    int o = tid;
    float s = 0.0f;
    for (int sy = 0; sy < 8; ++sy)
        #pragma unroll
        for (int sx = 0; sx < 8; ++sx) {
            int pix = (py * 8 + sy) * 64 + px * 8 + sx;
            s += b2f(xgb[((size_t)(b * N_ + pix)) * C_ + o]);
        }
    float v = s * (1.0f / 64.0f);
    float s1 = v, s2 = v * v;
    #pragma unroll
    for (int off = 32; off >= 1; off >>= 1) { s1 += __shfl_xor(s1, off); s2 += __shfl_xor(s2, off); }
    int wv = o >> 6, ln = o & 63;
    if (ln == 0) { r1[wv] = s1; r2[wv] = s2; }
    __syncthreads();
    float S1 = r1[0] + r1[1] + r1[2] + r1[3];
    float S2 = r2[0] + r2[1] + r2[2] + r2[3];
    float mu = S1 * (1.0f / 256.0f);
    float var = S2 * (1.0f / 256.0f) - mu * mu;
    xps[o] = (v - mu) * rsqrtf(var + 1e-5f) * g[o] + bta[o];
    __syncthreads();
    float a0 = kv_b[o];          // k column
    float a1 = kv_b[256 + o];    // v column
    const float4* xp4 = (const float4*)xps;
    const float4* wrow0 = (const float4*)(kv_w + (size_t)o * 256);
    const float4* wrow1 = (const float4*)(kv_w + (size_t)(256 + o) * 256);
    #pragma unroll 8
    for (int k4 = 0; k4 < 64; ++k4) {
        float4 xv = xp4[k4];
        float4 wa = wrow0[k4];
        float4 wb = wrow1[k4];
        a0 += xv.x * wa.x + xv.y * wa.y + xv.z * wa.z + xv.w * wa.w;
        a1 += xv.x * wb.x + xv.y * wb.y + xv.z * wb.z + xv.w * wb.w;
    }
    {
        float ss = a0 * a0;
        ss += __shfl_xor(ss, 1); ss += __shfl_xor(ss, 2); ss += __shfl_xor(ss, 4);
        ss += __shfl_xor(ss, 8); ss += __shfl_xor(ss, 16);
        a0 *= 1.0f / fmaxf(sqrtf(ss), 1e-12f);
    }
    kvp[(size_t)bp * 512 + o]       = a0;
    kvp[(size_t)bp * 512 + 256 + o] = a1;
}

// ---------------- MFMA fused attention: 2-tile loop + LDS-staged cpb gather (best-known) -------
// Round-8 post-mortem: register file (not LDS) caps occupancy at 3 waves/SIMD, and per-lane
// scattered global gathers from cpbt cost +14us vs the LDS-staged gather. This is the round-6/7
// configuration (best measured: 243-245us total, attn 54.4): cpb_s 16KB LDS stage (near-free
// random LDS gather, ~2-way bank aliasing), rpi indices hoisted to tile start, setprio around
// MFMA clusters, 2-tile amortized prologue. LDS 51784 B, VGPR 104.
__global__ __launch_bounds__(256) void attn_k(
    const u16* __restrict__ xb, const u16* __restrict__ qwb, const float* __restrict__ q_b,
    const float* __restrict__ kvk, const u16* __restrict__ kvv,
    const float* __restrict__ kvp, const int* __restrict__ rpi, const float* __restrict__ cpbt,
    const float* __restrict__ temp, const float* __restrict__ qe, const float* __restrict__ lt,
    const float* __restrict__ rpb, const float* __restrict__ lb,
    const float* __restrict__ slsin, u16* __restrict__ aob)
{
    __shared__ u16 kp_hi[64 * 40], kp_lo[64 * 40];
    __shared__ u16 vp_hi[32 * 72];
    __shared__ u16 ltb[16 * 32];
    __shared__ float S_w[4][16][76];
    __shared__ __align__(16) float cpb_s[4096];
    __shared__ float rpb_s[9], lb_s[9];

    int bid = blockIdx.x;
    int tq = bid & 31, h = (bid >> 5) & 7, b = bid >> 8;
    int tid = threadIdx.x, wave = tid >> 6, lane = tid & 63;
    int quad = lane >> 4, l16 = lane & 15;

    {
        int p = tid >> 2, dc = (tid & 3) * 8;
        const float* src = kvp + ((size_t)(b * P_ + p)) * 512 + h * 32 + dc;
        float4 k0 = *(const float4*)(src), k1 = *(const float4*)(src + 4);
        float4 v0 = *(const float4*)(src + 256), v1 = *(const float4*)(src + 260);
        float kf[8] = {k0.x,k0.y,k0.z,k0.w,k1.x,k1.y,k1.z,k1.w};
        float vf[8] = {v0.x,v0.y,v0.z,v0.w,v1.x,v1.y,v1.z,v1.w};
        #pragma unroll
        for (int j2 = 0; j2 < 4; ++j2) {
            float a = kf[2*j2], c = kf[2*j2+1];
            u32 pk = cvtpk(a, c);
            *(u32*)&kp_hi[p * 40 + dc + 2*j2] = pk;
            float ra = __uint_as_float(pk << 16);
            float rb = __uint_as_float(pk & 0xffff0000u);
            *(u32*)&kp_lo[p * 40 + dc + 2*j2] = cvtpk(a - ra, c - rb);
            // vp_hi uncompensated -> keep bit-exact RNE f2b
            vp_hi[(dc + 2*j2) * 72 + p]     = f2b(vf[2*j2]);
            vp_hi[(dc + 2*j2 + 1) * 72 + p] = f2b(vf[2*j2+1]);
        }
    }
    // stage this head's 16KB cpb slice (coalesced float4; transposed layout from prep_k)
    {
        const float4* cp4 = (const float4*)(cpbt + (size_t)h * 4096);
        float4* ds4 = (float4*)cpb_s;
        #pragma unroll
        for (int i = 0; i < 4; ++i) ds4[i * 256 + tid] = cp4[i * 256 + tid];
    }
    for (int t = tid; t < 512; t += 256) {
        int l = t & 15, d = t >> 4;
        ltb[l * 32 + d] = (l < 9) ? f2b(lt[h * 288 + d * 9 + l]) : (u16)0;
    }
    if (tid < 9) { rpb_s[tid] = rpb[h * 9 + tid]; lb_s[tid] = lb[h * 9 + tid]; }
    float tsc = log1pf(expf(temp[h]));
    __syncthreads();

    #pragma unroll 1
    for (int it = 0; it < 2; ++it) {
        int tile = tq * 2 + it;
        int n0w = tile * 64 + wave * 16;
        int y = tile;

        // ---- hoisted rpi gather: addresses depend only on n0w; issue before q-GEMM so the
        //      L2 latency hides under the 16-MFMA chain instead of stalling pool-logits ----
        int idxA[16];
        #pragma unroll
        for (int jt = 0; jt < 4; ++jt)
            #pragma unroll
            for (int r = 0; r < 4; ++r)
                idxA[jt * 4 + r] = rpi[(size_t)(n0w + quad * 4 + r) * 64 + jt * 16 + l16];

        // ---- fused q-GEMM: 64x32 slice via 16 MFMA ----
        f32x4 qacc[2] = {};
        {
            const u16* xrow = xb + ((size_t)(b * N_ + n0w + l16)) * 256 + quad * 8;
            const u16* qwr  = qwb + ((size_t)(h * 32 + l16)) * 256 + quad * 8;
            #pragma unroll
            for (int k0 = 0; k0 < 256; k0 += 32) {
                bf16x8 ax = *(const bf16x8*)(xrow + k0);
                bf16x8 bw0 = *(const bf16x8*)(qwr + k0);
                bf16x8 bw1 = *(const bf16x8*)(qwr + 16 * 256 + k0);
                qacc[0] = __builtin_amdgcn_mfma_f32_16x16x32_bf16(ax, bw0, qacc[0], 0, 0, 0);
                qacc[1] = __builtin_amdgcn_mfma_f32_16x16x32_bf16(ax, bw1, qacc[1], 0, 0, 0);
            }
        }
        {
            float qb0 = q_b[h * 32 + l16], qb1 = q_b[h * 32 + 16 + l16];
            float qe0 = qe[h * 32 + l16],  qe1 = qe[h * 32 + 16 + l16];
            #pragma unroll
            for (int r = 0; r < 4; ++r) {
                int p = quad * 4 + r;
                float v0 = qacc[0][r] + qb0, v1 = qacc[1][r] + qb1;
                float s = v0 * v0 + v1 * v1;
                s += __shfl_xor(s, 1); s += __shfl_xor(s, 2);
                s += __shfl_xor(s, 4); s += __shfl_xor(s, 8);
                float inv = 1.0f / fmaxf(sqrtf(s), 1e-12f);
                v0 *= inv; v1 *= inv;
                float sc = tsc * slsin[n0w + p];
                S_w[wave][p][40 + l16]      = (v0 + qe0) * sc;
                S_w[wave][p][40 + 16 + l16] = (v1 + qe1) * sc;
            }
        }
        // ---- rebuild per-lane fragments (A-layout) from qs scratch in S_w cols 40..71 ----
        bf16x8 qs_hi, qs_lo, qn_b;
        float qsr[8];
        {
            *(float4*)&qsr[0] = *(const float4*)&S_w[wave][l16][40 + quad * 8];
            *(float4*)&qsr[4] = *(const float4*)&S_w[wave][l16][40 + quad * 8 + 4];
            float invs = 1.0f / (tsc * slsin[n0w + l16]);
            const float* qep = qe + h * 32 + quad * 8;
            float4 e0 = *(const float4*)qep, e1 = *(const float4*)(qep + 4);
            float ef[8] = {e0.x,e0.y,e0.z,e0.w,e1.x,e1.y,e1.z,e1.w};
            U8 hiu, lou;
            #pragma unroll
            for (int j2 = 0; j2 < 4; ++j2) {
                float a = qsr[2*j2], c = qsr[2*j2+1];
                u32 pk = cvtpk(a, c);
                hiu.u[j2] = pk;
                float ra = __uint_as_float(pk << 16);
                float rb = __uint_as_float(pk & 0xffff0000u);
                lou.u[j2] = cvtpk(a - ra, c - rb);
            }
            qs_hi = hiu.v; qs_lo = lou.v;
            #pragma unroll
            for (int j = 0; j < 8; ++j)
                qn_b[j] = f2bs(qsr[j] * invs - ef[j]);   // uncompensated -> exact RNE
        }
        // ---- pool logits (12 MFMA, compensated) + LDS-gathered bias ----
        __builtin_amdgcn_s_setprio(1);
        #pragma unroll
        for (int jt = 0; jt < 4; ++jt) {
            bf16x8 bh = *(const bf16x8*)&kp_hi[(jt * 16 + l16) * 40 + quad * 8];
            bf16x8 bl = *(const bf16x8*)&kp_lo[(jt * 16 + l16) * 40 + quad * 8];
            f32x4 a = {};
            a = __builtin_amdgcn_mfma_f32_16x16x32_bf16(qs_lo, bh, a, 0, 0, 0);
            a = __builtin_amdgcn_mfma_f32_16x16x32_bf16(qs_hi, bl, a, 0, 0, 0);
            a = __builtin_amdgcn_mfma_f32_16x16x32_bf16(qs_hi, bh, a, 0, 0, 0);
            #pragma unroll
            for (int r = 0; r < 4; ++r) {
                int pix = quad * 4 + r;
                S_w[wave][pix][jt * 16 + l16] = a[r] + cpb_s[idxA[jt * 4 + r]];
            }
        }
        __builtin_amdgcn_s_setprio(0);
        // ---- learnable-token logits (1 MFMA) ----
        f32x4 accL;
        {
            bf16x8 ltf = *(const bf16x8*)&ltb[l16 * 32 + quad * 8];
            f32x4 z = {};
            accL = __builtin_amdgcn_mfma_f32_16x16x32_bf16(qn_b, ltf, z, 0, 0, 0);
        }
        // ---- local 3x3 logits: register qs + cross-quad shuffle reduce ----
        #pragma unroll
        for (int l = 0; l < 9; ++l) {
            int n = n0w + l16, x = n & 63;
            int ny = y + l / 3 - 1, nx = x + (l % 3) - 1;
            bool ok = ((unsigned)ny < 64u) && ((unsigned)nx < 64u);
            int nn = ok ? ny * 64 + nx : n;
            const float4* kb = (const float4*)(kvk + ((size_t)(b * N_ + nn)) * 256 + h * 32 + quad * 8);
            float4 k0v = kb[0], k1v = kb[1];
            float part = qsr[0]*k0v.x + qsr[1]*k0v.y + qsr[2]*k0v.z + qsr[3]*k0v.w
                       + qsr[4]*k1v.x + qsr[5]*k1v.y + qsr[6]*k1v.z + qsr[7]*k1v.w;
            part += __shfl_xor(part, 16);
            part += __shfl_xor(part, 32);
            if (quad == 0) S_w[wave][l16][64 + l] = ok ? (part + rpb_s[l]) : NEG_;
        }
        // ---- re-init NEG pad (softmax of previous tile / qs scratch overwrote it) ----
        if (quad == 0) { S_w[wave][l16][73] = NEG_; S_w[wave][l16][74] = NEG_; S_w[wave][l16][75] = NEG_; }
        // ---- softmax over 73 (4 lanes per pixel, 19 cols each) ----
        {
            int pix = lane >> 2, c0 = (lane & 3) * 19;
            float vals[19]; float mx = NEG_;
            #pragma unroll
            for (int i = 0; i < 19; ++i) { vals[i] = S_w[wave][pix][c0 + i]; mx = fmaxf(mx, vals[i]); }
            mx = fmaxf(mx, __shfl_xor(mx, 1));
            mx = fmaxf(mx, __shfl_xor(mx, 2));
            float sm = 0.0f;
            #pragma unroll
            for (int i = 0; i < 19; ++i) { vals[i] = __expf(vals[i] - mx); sm += vals[i]; }
            sm += __shfl_xor(sm, 1); sm += __shfl_xor(sm, 2);
            float inv = 1.0f / sm;
            #pragma unroll
            for (int i = 0; i < 19; ++i) S_w[wave][pix][c0 + i] = vals[i] * inv;
        }
        // ---- combined local weights overwrite S_w cols 64..72 ----
        if (l16 < 9) {
            #pragma unroll
            for (int r = 0; r < 4; ++r) {
                int pix = quad * 4 + r;
                int n = n0w + pix, x = n & 63;
                int ny = y + l16 / 3 - 1, nx = x + (l16 % 3) - 1;
                bool ok = ((unsigned)ny < 64u) && ((unsigned)nx < 64u);
                float prev = S_w[wave][pix][64 + l16];
                S_w[wave][pix][64 + l16] = ok ? (accL[r] + lb_s[l16] + prev) : 0.0f;
            }
        }
        // ---- PV (8 MFMA: (w_hi + w_lo) x v_hi) ----
        f32x4 accO[2] = {};
        __builtin_amdgcn_s_setprio(1);
        #pragma unroll
        for (int kc = 0; kc < 2; ++kc) {
            float wf[8];
            *(float4*)&wf[0] = *(const float4*)&S_w[wave][l16][kc * 32 + quad * 8];
            *(float4*)&wf[4] = *(const float4*)&S_w[wave][l16][kc * 32 + quad * 8 + 4];
            U8 hiu, lou;
            #pragma unroll
            for (int j2 = 0; j2 < 4; ++j2) {
                float a = wf[2*j2], c = wf[2*j2+1];
                u32 pk = cvtpk(a, c);
                hiu.u[j2] = pk;
                float ra = __uint_as_float(pk << 16);
                float rb = __uint_as_float(pk & 0xffff0000u);
                lou.u[j2] = cvtpk(a - ra, c - rb);
            }
            bf16x8 w_hi = hiu.v, w_lo = lou.v;
            #pragma unroll
            for (int nt = 0; nt < 2; ++nt) {
                bf16x8 vh = *(const bf16x8*)&vp_hi[(nt * 16 + l16) * 72 + kc * 32 + quad * 8];
                accO[nt] = __builtin_amdgcn_mfma_f32_16x16x32_bf16(w_lo, vh, accO[nt], 0, 0, 0);
                accO[nt] = __builtin_amdgcn_mfma_f32_16x16x32_bf16(w_hi, vh, accO[nt], 0, 0, 0);
            }
        }
        __builtin_amdgcn_s_setprio(0);
        // ---- local-V: shared neighbor columns per quad (18 cols x 2 dims) ----
        {
            int xq0 = wave * 16 + quad * 4;     // x of pixel r=0
            #pragma unroll
            for (int dy = -1; dy <= 1; ++dy) {
                int ny = y + dy;
                bool rowOK = ((unsigned)ny < 64u);
                #pragma unroll
                for (int c = 0; c < 6; ++c) {
                    int xc = xq0 - 1 + c;
                    bool ok = rowOK && ((unsigned)xc < 64u);
                    int nn = ok ? ny * 64 + xc : 0;
                    const u16* vb = kvv + ((size_t)(b * N_ + nn)) * 256 + h * 32;
                    float v0 = b2f(vb[l16]);
                    float v1 = b2f(vb[16 + l16]);
                    #pragma unroll
                    for (int r = 0; r < 4; ++r) {
                        int dxr = c - 1 - r;
                        if (dxr >= -1 && dxr <= 1) {
                            int l = (dy + 1) * 3 + dxr + 1;
                            float aw = S_w[wave][quad * 4 + r][64 + l];
                            accO[0][r] += aw * v0;
                            accO[1][r] += aw * v1;
                        }
                    }
                }
            }
        }
        #pragma unroll
        for (int nt = 0; nt < 2; ++nt)
            #pragma unroll
            for (int r = 0; r < 4; ++r) {
                int n = n0w + quad * 4 + r;
                aob[((size_t)(b * N_ + n)) * C_ + h * 32 + nt * 16 + l16] = f2b(accO[nt][r]);
            }
    }
}

extern "C" void kernel_launch(void* const* d_in, const int* in_sizes, int n_in,
                              void* d_out, int out_size, void* d_ws, size_t ws_size,
                              hipStream_t stream) {
    const float* x      = (const float*)d_in[0];
    const int*   rpi    = (const int*)d_in[1];
    const float* table  = (const float*)d_in[2];
    const float* q_w    = (const float*)d_in[3];
    const float* q_b    = (const float*)d_in[4];
    const float* kv_w   = (const float*)d_in[5];
    const float* kv_b   = (const float*)d_in[6];
    const float* temp   = (const float*)d_in[7];
    const float* qe     = (const float*)d_in[8];
    const float* proj_w = (const float*)d_in[9];
    const float* proj_b = (const float*)d_in[10];
    const float* sr_w   = (const float*)d_in[11];
    const float* sr_b   = (const float*)d_in[12];
    const float* norm_g = (const float*)d_in[13];
    const float* norm_b = (const float*)d_in[14];
    const float* cpb1_w = (const float*)d_in[15];
    const float* cpb1_b = (const float*)d_in[16];
    const float* cpb2_w = (const float*)d_in[17];
    const float* cpb2_b = (const float*)d_in[18];
    const float* rpb    = (const float*)d_in[19];
    const float* lt     = (const float*)d_in[20];
    const float* lb     = (const float*)d_in[21];
    const float* sls    = (const float*)d_in[22];

    float* ws   = (float*)d_ws;
    float* kvk  = ws;                                   // B*N*C fp32 (k, l2normed)
    float* kvp  = kvk + (size_t)B_ * N_ * C_;           // B*P*2C fp32
    float* cpb  = kvp + (size_t)B_ * P_ * 2 * C_;       // NH*T fp32 (transposed: [h][t])
    u16*   xb   = (u16*)(cpb + (size_t)T_ * NH_);       // B*N*C bf16
    u16*   wfb  = xb  + (size_t)B_ * N_ * C_;           // 1024*256 bf16 (q;kv;sr)
    u16*   pwb  = wfb + (size_t)1024 * C_;              // C*C bf16
    u16*   kvv  = pwb + (size_t)C_ * C_;                // B*N*C bf16 (v)
    u16*   xgb  = kvv + (size_t)B_ * N_ * C_;           // B*N*C bf16 (gelu out; reused as attn out)
    u16*   aob  = xgb;

    dim3 blk(256);

    prep_k<<<dim3(4432), blk, 0, stream>>>(x, q_w, kv_w, sr_w, proj_w, xb, wfb, pwb,
                                           table, cpb1_w, cpb1_b, cpb2_w, cpb2_b, cpb);
    gemm_big_k<0><<<dim3(768), blk, 0, stream>>>(xb, wfb, nullptr, kv_b, sr_b, kvk, kvv, xgb, nullptr);
    poolkv_k<<<dim3(256), blk, 0, stream>>>(xgb, norm_g, norm_b, kv_w, kv_b, kvp);
    attn_k<<<dim3(B_ * NH_ * 32), blk, 0, stream>>>(xb, wfb, q_b, kvk, kvv, kvp, rpi, cpb,
                                                    temp, qe, lt, rpb, lb, sls, aob);
    gemm_big_k<1><<<dim3(1024), blk, 0, stream>>>(aob, pwb, proj_b, nullptr, nullptr,
                                                  nullptr, nullptr, nullptr, (float*)d_out);
}